// Round 1
// baseline (1277.903 us; speedup 1.0000x reference)
//
#include <hip/hip_runtime.h>
#include <stdint.h>

#define NB 20

__device__ __forceinline__ float bf_lo(uint32_t u) { return __uint_as_float(u << 16); }
__device__ __forceinline__ float bf_hi(uint32_t u) { return __uint_as_float(u & 0xffff0000u); }
__device__ __forceinline__ uint32_t f2bf(float f) {
    uint32_t u = __float_as_uint(f);
    return (u + 0x7fffu + ((u >> 16) & 1u)) >> 16;  // RNE
}
__device__ __forceinline__ uint32_t pack_bf2(float a, float b) {
    return f2bf(a) | (f2bf(b) << 16);
}
__device__ __forceinline__ float silu_f(float x) { return x / (1.f + __expf(-x)); }

// ---------------------------------------------------------------------------
// prep: M = W2 @ Wu (packed bf16 pairs, [128][64] uints), cvec = b2 @ Wu (fp32)
// grid 129 x 64
// ---------------------------------------------------------------------------
__global__ void prep_kernel(const float* __restrict__ W2, const float* __restrict__ b2,
                            const float* __restrict__ Wu,
                            uint32_t* __restrict__ Mpk, float* __restrict__ cvec) {
    int q = threadIdx.x;           // 0..63 -> cols 2q, 2q+1
    int k = blockIdx.x;            // 0..127 rows of M; 128 -> cvec
    const float* row = (k < 128) ? (W2 + k * 128) : b2;
    float acc0 = 0.f, acc1 = 0.f;
    for (int j = 0; j < 128; ++j) {
        float w = row[j];
        float2 wu = *(const float2*)(Wu + j * 128 + 2 * q);
        acc0 = fmaf(w, wu.x, acc0);
        acc1 = fmaf(w, wu.y, acc1);
    }
    if (k < 128) {
        Mpk[k * 64 + q] = pack_bf2(acc0, acc1);
    } else {
        cvec[2 * q] = acc0;
        cvec[2 * q + 1] = acc1;
    }
}

// ---------------------------------------------------------------------------
// kernel A: P[e][0:256] bf16, P1 = edge_attr @ W1[0:128,:], P2 = @ W1[128:256,:]
// block = 256 threads (thread = output col c in 0..255), 32 edges per block
// ---------------------------------------------------------------------------
__global__ void __launch_bounds__(256) kA(const float* __restrict__ edge_attr,
                                          const float* __restrict__ W1,
                                          uint16_t* __restrict__ Pb, int E) {
    __shared__ float a_lds[32 * 128];
    const int tid = threadIdx.x;
    const int e0 = blockIdx.x * 32;
    const int nE = min(32, E - e0);

    // stage A tile (32 edges x 128) as float4
    {
        const float4* src = (const float4*)(edge_attr + (size_t)e0 * 128);
        int lim = nE * 32;
        for (int idx = tid; idx < lim; idx += 256)
            ((float4*)a_lds)[idx] = src[idx];
    }
    __syncthreads();

    const int c = tid;  // output col 0..255
    const float* wp = (c < 128) ? (W1 + c) : (W1 + 128 * 128 + (c - 128));

    float acc[32];
#pragma unroll
    for (int e = 0; e < 32; ++e) acc[e] = 0.f;

    for (int k = 0; k < 128; k += 4) {
        float w0 = wp[(k + 0) * 128];
        float w1 = wp[(k + 1) * 128];
        float w2 = wp[(k + 2) * 128];
        float w3 = wp[(k + 3) * 128];
#pragma unroll
        for (int e = 0; e < 32; ++e) {
            float4 a = *(const float4*)(a_lds + e * 128 + k);
            acc[e] = fmaf(a.x, w0, acc[e]);
            acc[e] = fmaf(a.y, w1, acc[e]);
            acc[e] = fmaf(a.z, w2, acc[e]);
            acc[e] = fmaf(a.w, w3, acc[e]);
        }
    }
#pragma unroll
    for (int e = 0; e < 32; ++e) {
        if (e < nE) Pb[(size_t)(e0 + e) * 256 + c] = (uint16_t)f2bf(acc[e]);
    }
}

// ---------------------------------------------------------------------------
// kernel B: per-triplet angle MLP + pre = P1[e_ij]+P2[e_ik]+af@W1c+b1, silu,
// atomic scatter into S (= d_out) and cnt. 256 triplets per block.
// ---------------------------------------------------------------------------
__global__ void __launch_bounds__(256) kB(const int* __restrict__ tbe,
                                          const float* __restrict__ evec,
                                          const float* __restrict__ Wa1,
                                          const float* __restrict__ ba1,
                                          const float* __restrict__ Wa2,
                                          const float* __restrict__ ba2,
                                          const float* __restrict__ W1,
                                          const float* __restrict__ b1,
                                          const uint32_t* __restrict__ Ppk,
                                          float* __restrict__ S,
                                          uint32_t* __restrict__ cnt, int T) {
    __shared__ float af_s[256 * 21];     // padded stride 21: conflict-free
    __shared__ int e1_s[256];
    __shared__ int e2_s[256];
    __shared__ float w1c_s[NB * 128];    // W1 rows 256..275
    __shared__ float wa1_s[60], ba1_s[NB], wa2_s[400], ba2_s[NB];

    const int tid = threadIdx.x;
    for (int i = tid; i < NB * 128; i += 256) w1c_s[i] = W1[256 * 128 + i];
    for (int i = tid; i < 400; i += 256) wa2_s[i] = Wa2[i];
    if (tid < 60) wa1_s[tid] = Wa1[tid];
    if (tid < NB) { ba1_s[tid] = ba1[tid]; ba2_s[tid] = ba2[tid]; }

    const int gt = blockIdx.x * 256 + tid;
    const bool valid = (gt < T);
    int e1 = 0, e2 = 0;
    if (valid) {
        int2 ee = ((const int2*)tbe)[gt];
        e1 = ee.x; e2 = ee.y;
    }
    __syncthreads();  // weights staged

    if (valid) {
        float ax = evec[e1 * 3], ay = evec[e1 * 3 + 1], az = evec[e1 * 3 + 2];
        float bx = evec[e2 * 3], by = evec[e2 * 3 + 1], bz = evec[e2 * 3 + 2];
        float li = fmaxf(sqrtf(ax * ax + ay * ay + az * az), 1e-6f);
        float lk = fmaxf(sqrtf(bx * bx + by * by + bz * bz), 1e-6f);
        float ct = (ax * bx + ay * by + az * bz) / (li * lk);
        ct = fminf(fmaxf(ct, -1.f), 1.f);

        float h[NB];
#pragma unroll
        for (int o = 0; o < NB; ++o) {
            float z = fmaf(li, wa1_s[o], fmaf(lk, wa1_s[20 + o], fmaf(ct, wa1_s[40 + o], ba1_s[o])));
            h[o] = silu_f(z);
        }
        float af[NB];
#pragma unroll
        for (int o2 = 0; o2 < NB; ++o2) af[o2] = ba2_s[o2];
#pragma unroll
        for (int o = 0; o < NB; ++o) {
#pragma unroll
            for (int o2 = 0; o2 < NB; ++o2) af[o2] = fmaf(h[o], wa2_s[o * 20 + o2], af[o2]);
        }
#pragma unroll
        for (int o = 0; o < NB; ++o) af_s[tid * 21 + o] = af[o];
        atomicAdd(&cnt[e1], 1u);
        e1_s[tid] = e1;
        e2_s[tid] = e2;
    } else {
        e1_s[tid] = -1;
        e2_s[tid] = 0;
    }
    __syncthreads();

    // phase 2: wave per triplet, lane covers cols (2*lane, 2*lane+1)
    const int lane = tid & 63;
    const int tbase = (tid >> 6) * 64;
    const float2 b1v = ((const float2*)b1)[lane];
    const float2* w1c2 = (const float2*)w1c_s;

    int ce1 = e1_s[tbase], ce2 = e2_s[tbase];
    bool cval = (ce1 >= 0);
    int a1 = cval ? ce1 : 0, a2 = cval ? ce2 : 0;
    uint32_t p1 = Ppk[a1 * 128 + lane];
    uint32_t p2 = Ppk[a2 * 128 + 64 + lane];

    for (int i = 0; i < 64; ++i) {
        const int t = tbase + i;
        const uint32_t q1 = p1, q2 = p2;
        const int se = a1;
        const bool sv = cval;
        if (i < 63) {  // prefetch next triplet's P rows
            int ne1 = e1_s[t + 1], ne2 = e2_s[t + 1];
            cval = (ne1 >= 0);
            a1 = cval ? ne1 : 0;
            a2 = cval ? ne2 : 0;
            p1 = Ppk[a1 * 128 + lane];
            p2 = Ppk[a2 * 128 + 64 + lane];
        }
        float x0 = bf_lo(q1) + bf_lo(q2) + b1v.x;
        float x1 = bf_hi(q1) + bf_hi(q2) + b1v.y;
        const float* afp = af_s + t * 21;
#pragma unroll
        for (int k = 0; k < NB; ++k) {
            float a = afp[k];
            float2 w = w1c2[k * 64 + lane];
            x0 = fmaf(a, w.x, x0);
            x1 = fmaf(a, w.y, x1);
        }
        float s0 = silu_f(x0), s1 = silu_f(x1);
        if (sv) {
            unsafeAtomicAdd(&S[se * 128 + 2 * lane], s0);
            unsafeAtomicAdd(&S[se * 128 + 2 * lane + 1], s1);
        }
    }
}

// ---------------------------------------------------------------------------
// kernel C: out = S @ M + cnt*cvec + bu, in-place on d_out. 4 edges / iter.
// ---------------------------------------------------------------------------
__global__ void __launch_bounds__(256) kC(const uint32_t* __restrict__ Mpk,
                                          const float* __restrict__ cvec,
                                          const float* __restrict__ bu,
                                          const uint32_t* __restrict__ cnt,
                                          float* __restrict__ S, int E) {
    __shared__ uint32_t M_s[128 * 64];
    __shared__ float s_s[4][128];
    const int tid = threadIdx.x;
    for (int i = tid; i < 8192; i += 256) M_s[i] = Mpk[i];

    const int sel = tid >> 6;   // which of 4 edges
    const int q = tid & 63;     // col pair -> cols 2q, 2q+1
    const float cv0 = cvec[2 * q], cv1 = cvec[2 * q + 1];
    const float bu0 = bu[2 * q], bu1 = bu[2 * q + 1];

    const int ng = (E + 3) >> 2;
    for (int g = blockIdx.x; g < ng; g += gridDim.x) {
        const int ebase = g * 4;
        const int nrow = min(4, E - ebase) * 128;
        __syncthreads();  // protect s_s reuse
        for (int i = tid; i < nrow; i += 256) ((float*)s_s)[i] = S[(size_t)ebase * 128 + i];
        __syncthreads();
        const int e = ebase + sel;
        if (e < E) {
            const float fc = (float)cnt[e];
            float acc0 = fmaf(fc, cv0, bu0);
            float acc1 = fmaf(fc, cv1, bu1);
#pragma unroll 8
            for (int k = 0; k < 128; ++k) {
                uint32_t m = M_s[k * 64 + q];
                float s = s_s[sel][k];
                acc0 = fmaf(s, bf_lo(m), acc0);
                acc1 = fmaf(s, bf_hi(m), acc1);
            }
            float2 o;
            o.x = acc0;
            o.y = acc1;
            ((float2*)S)[(size_t)e * 64 + q] = o;
        }
    }
}

// ---------------------------------------------------------------------------
extern "C" void kernel_launch(void* const* d_in, const int* in_sizes, int n_in,
                              void* d_out, int out_size, void* d_ws, size_t ws_size,
                              hipStream_t stream) {
    const float* edge_attr = (const float*)d_in[0];
    // d_in[1]: three_body_indices — unused by the reference computation
    const int* tbe = (const int*)d_in[2];
    const float* evec = (const float*)d_in[3];
    const float* Wa1 = (const float*)d_in[4];
    const float* ba1 = (const float*)d_in[5];
    const float* Wa2 = (const float*)d_in[6];
    const float* ba2 = (const float*)d_in[7];
    const float* W1 = (const float*)d_in[8];
    const float* b1 = (const float*)d_in[9];
    const float* W2 = (const float*)d_in[10];
    const float* b2 = (const float*)d_in[11];
    const float* Wu = (const float*)d_in[12];
    const float* bu = (const float*)d_in[13];

    const int E = in_sizes[0] / 128;
    const int T = in_sizes[2] / 2;
    float* S = (float*)d_out;

    char* ws = (char*)d_ws;
    uint32_t* Ppk = (uint32_t*)ws;                                 // E*512 bytes (bf16 E x 256)
    uint32_t* cnt = (uint32_t*)(ws + (size_t)E * 512);             // E*4
    uint32_t* Mpk = (uint32_t*)(ws + (size_t)E * 516);             // 32 KiB
    float* cvec = (float*)(ws + (size_t)E * 516 + 32768);          // 512 B

    hipMemsetAsync(d_out, 0, (size_t)E * 512, stream);
    hipMemsetAsync(cnt, 0, (size_t)E * 4, stream);

    prep_kernel<<<129, 64, 0, stream>>>(W2, b2, Wu, Mpk, cvec);
    kA<<<(E + 31) / 32, 256, 0, stream>>>(edge_attr, W1, (uint16_t*)Ppk, E);
    kB<<<(T + 255) / 256, 256, 0, stream>>>(tbe, evec, Wa1, ba1, Wa2, ba2, W1, b1,
                                            Ppk, S, cnt, T);
    kC<<<512, 256, 0, stream>>>(Mpk, cvec, bu, cnt, S, E);
}

// Round 2
// 812.418 us; speedup vs baseline: 1.5730x; 1.5730x over previous
//
#include <hip/hip_runtime.h>
#include <stdint.h>

#define NB 20

__device__ __forceinline__ float bf_lo(uint32_t u) { return __uint_as_float(u << 16); }
__device__ __forceinline__ float bf_hi(uint32_t u) { return __uint_as_float(u & 0xffff0000u); }
__device__ __forceinline__ uint32_t f2bf(float f) {
    uint32_t u = __float_as_uint(f);
    return (u + 0x7fffu + ((u >> 16) & 1u)) >> 16;  // RNE
}
__device__ __forceinline__ uint32_t pack_bf2(float a, float b) {
    return f2bf(a) | (f2bf(b) << 16);
}
__device__ __forceinline__ float silu_f(float x) { return x / (1.f + __expf(-x)); }

// ---------------------------------------------------------------------------
// prep: M = W2 @ Wu (packed bf16 pairs, [128][64] uints), cvec = b2 @ Wu (fp32)
// ---------------------------------------------------------------------------
__global__ void prep_kernel(const float* __restrict__ W2, const float* __restrict__ b2,
                            const float* __restrict__ Wu,
                            uint32_t* __restrict__ Mpk, float* __restrict__ cvec) {
    int q = threadIdx.x;           // 0..63 -> cols 2q, 2q+1
    int k = blockIdx.x;            // 0..127 rows of M; 128 -> cvec
    const float* row = (k < 128) ? (W2 + k * 128) : b2;
    float acc0 = 0.f, acc1 = 0.f;
    for (int j = 0; j < 128; ++j) {
        float w = row[j];
        float2 wu = *(const float2*)(Wu + j * 128 + 2 * q);
        acc0 = fmaf(w, wu.x, acc0);
        acc1 = fmaf(w, wu.y, acc1);
    }
    if (k < 128) {
        Mpk[k * 64 + q] = pack_bf2(acc0, acc1);
    } else {
        cvec[2 * q] = acc0;
        cvec[2 * q + 1] = acc1;
    }
}

// ---------------------------------------------------------------------------
// kernel A: P[e][0:256] bf16, P1 = edge_attr @ W1[0:128,:], P2 = @ W1[128:256,:]
// ---------------------------------------------------------------------------
__global__ void __launch_bounds__(256) kA(const float* __restrict__ edge_attr,
                                          const float* __restrict__ W1,
                                          uint16_t* __restrict__ Pb, int E) {
    __shared__ float a_lds[32 * 128];
    const int tid = threadIdx.x;
    const int e0 = blockIdx.x * 32;
    const int nE = min(32, E - e0);

    {
        const float4* src = (const float4*)(edge_attr + (size_t)e0 * 128);
        int lim = nE * 32;
        for (int idx = tid; idx < lim; idx += 256)
            ((float4*)a_lds)[idx] = src[idx];
    }
    __syncthreads();

    const int c = tid;
    const float* wp = (c < 128) ? (W1 + c) : (W1 + 128 * 128 + (c - 128));

    float acc[32];
#pragma unroll
    for (int e = 0; e < 32; ++e) acc[e] = 0.f;

    for (int k = 0; k < 128; k += 4) {
        float w0 = wp[(k + 0) * 128];
        float w1 = wp[(k + 1) * 128];
        float w2 = wp[(k + 2) * 128];
        float w3 = wp[(k + 3) * 128];
#pragma unroll
        for (int e = 0; e < 32; ++e) {
            float4 a = *(const float4*)(a_lds + e * 128 + k);
            acc[e] = fmaf(a.x, w0, acc[e]);
            acc[e] = fmaf(a.y, w1, acc[e]);
            acc[e] = fmaf(a.z, w2, acc[e]);
            acc[e] = fmaf(a.w, w3, acc[e]);
        }
    }
#pragma unroll
    for (int e = 0; e < 32; ++e) {
        if (e < nE) Pb[(size_t)(e0 + e) * 256 + c] = (uint16_t)f2bf(acc[e]);
    }
}

// ---------------------------------------------------------------------------
// counting sort by e_ij: hist -> scan (3 kernels) -> scatter of e_ik
// ---------------------------------------------------------------------------
__global__ void khist(const int* __restrict__ tbe, uint32_t* __restrict__ cnt, int T) {
    int t = blockIdx.x * blockDim.x + threadIdx.x;
    int stride = gridDim.x * blockDim.x;
    for (; t < T; t += stride) {
        int2 ee = ((const int2*)tbe)[t];
        atomicAdd(&cnt[ee.x], 1u);
    }
}

__global__ void scanA(const uint32_t* __restrict__ cnt, uint32_t* __restrict__ bsum, int E) {
    __shared__ uint32_t s[256];
    int tid = threadIdx.x;
    int e = blockIdx.x * 256 + tid;
    s[tid] = (e < E) ? cnt[e] : 0u;
    __syncthreads();
    for (int off = 128; off > 0; off >>= 1) {
        if (tid < off) s[tid] += s[tid + off];
        __syncthreads();
    }
    if (tid == 0) bsum[blockIdx.x] = s[0];
}

__global__ void scanB(uint32_t* __restrict__ bsum, int n) {
    __shared__ uint32_t s[512];
    int tid = threadIdx.x;
    s[tid] = (tid < n) ? bsum[tid] : 0u;
    __syncthreads();
    for (int off = 1; off < 512; off <<= 1) {
        uint32_t a = (tid >= off) ? s[tid - off] : 0u;
        __syncthreads();
        s[tid] += a;
        __syncthreads();
    }
    if (tid < n) bsum[tid] = (tid > 0) ? s[tid - 1] : 0u;
}

__global__ void scanC(const uint32_t* __restrict__ cnt, const uint32_t* __restrict__ bsum,
                      uint32_t* __restrict__ offs, int E) {
    __shared__ uint32_t s[256];
    int tid = threadIdx.x;
    int e = blockIdx.x * 256 + tid;
    uint32_t v = (e < E) ? cnt[e] : 0u;
    s[tid] = v;
    __syncthreads();
    for (int off = 1; off < 256; off <<= 1) {
        uint32_t a = (tid >= off) ? s[tid - off] : 0u;
        __syncthreads();
        s[tid] += a;
        __syncthreads();
    }
    if (e < E) offs[e] = bsum[blockIdx.x] + s[tid] - v;   // exclusive start
}

__global__ void kscat(const int* __restrict__ tbe, uint32_t* __restrict__ offs,
                      uint32_t* __restrict__ sorted, int T) {
    int t = blockIdx.x * blockDim.x + threadIdx.x;
    int stride = gridDim.x * blockDim.x;
    for (; t < T; t += stride) {
        int2 ee = ((const int2*)tbe)[t];
        uint32_t pos = atomicAdd(&offs[ee.x], 1u);   // post-scatter: offs[e] = segment END
        sorted[pos] = (uint32_t)ee.y;
    }
}

// ---------------------------------------------------------------------------
// kernel B3: one wave per edge group. Accumulate silu(pre) over the group's
// triplets in registers, write S row once. No atomics.
// ---------------------------------------------------------------------------
__global__ void __launch_bounds__(256) kB3(const uint32_t* __restrict__ sorted,
                                           const uint32_t* __restrict__ offs,
                                           const float* __restrict__ evec,
                                           const float* __restrict__ Wa1,
                                           const float* __restrict__ ba1,
                                           const float* __restrict__ Wa2,
                                           const float* __restrict__ ba2,
                                           const float* __restrict__ W1,
                                           const float* __restrict__ b1,
                                           const uint32_t* __restrict__ Ppk,
                                           float* __restrict__ S, int E) {
    __shared__ float w1c_s[NB * 128];
    __shared__ float wa1_s[60], ba1_s[NB], wa2_s[400], ba2_s[NB];
    __shared__ float af_s[4][64 * 21];
    __shared__ uint32_t e2_s[4][64];

    const int tid = threadIdx.x;
    for (int i = tid; i < NB * 128; i += 256) w1c_s[i] = W1[256 * 128 + i];
    for (int i = tid; i < 400; i += 256) wa2_s[i] = Wa2[i];
    if (tid < 60) wa1_s[tid] = Wa1[tid];
    if (tid < NB) { ba1_s[tid] = ba1[tid]; ba2_s[tid] = ba2[tid]; }
    __syncthreads();

    const int wave = tid >> 6, lane = tid & 63;
    const int e = blockIdx.x * 4 + wave;
    if (e >= E) return;   // no barriers below — safe divergence

    const uint32_t start = (e > 0) ? offs[e - 1] : 0u;
    const uint32_t end = offs[e];
    const int n = (int)(end - start);

    const float2 b1v = ((const float2*)b1)[lane];
    const uint32_t p1 = Ppk[(size_t)e * 128 + lane];
    const float p1lo = bf_lo(p1) + b1v.x;
    const float p1hi = bf_hi(p1) + b1v.y;
    float acc0 = 0.f, acc1 = 0.f;

    const float ax = evec[e * 3], ay = evec[e * 3 + 1], az = evec[e * 3 + 2];
    const float li = fmaxf(sqrtf(ax * ax + ay * ay + az * az), 1e-6f);
    const float2* w1c2 = (const float2*)w1c_s;
    float* afw = af_s[wave];

    for (int c0 = 0; c0 < n; c0 += 64) {
        const int i = c0 + lane;
        if (i < n) {
            const uint32_t e2 = sorted[start + i];
            e2_s[wave][lane] = e2;
            const float bx = evec[e2 * 3], by = evec[e2 * 3 + 1], bz = evec[e2 * 3 + 2];
            const float lk = fmaxf(sqrtf(bx * bx + by * by + bz * bz), 1e-6f);
            float ct = (ax * bx + ay * by + az * bz) / (li * lk);
            ct = fminf(fmaxf(ct, -1.f), 1.f);
            float h[NB];
#pragma unroll
            for (int o = 0; o < NB; ++o) {
                float z = fmaf(li, wa1_s[o], fmaf(lk, wa1_s[20 + o], fmaf(ct, wa1_s[40 + o], ba1_s[o])));
                h[o] = silu_f(z);
            }
            float af[NB];
#pragma unroll
            for (int o2 = 0; o2 < NB; ++o2) af[o2] = ba2_s[o2];
#pragma unroll
            for (int o = 0; o < NB; ++o) {
#pragma unroll
                for (int o2 = 0; o2 < NB; ++o2) af[o2] = fmaf(h[o], wa2_s[o * 20 + o2], af[o2]);
            }
#pragma unroll
            for (int o = 0; o < NB; ++o) afw[lane * 21 + o] = af[o];
        }
        // within-wave LDS producer->consumer: drain ds_writes, pin ordering
        asm volatile("s_waitcnt lgkmcnt(0)" ::: "memory");
        __builtin_amdgcn_sched_barrier(0);

        const int m = min(64, n - c0);
        uint32_t p2n = Ppk[(size_t)e2_s[wave][0] * 128 + 64 + lane];
        for (int i2 = 0; i2 < m; ++i2) {
            const uint32_t p2 = p2n;
            if (i2 + 1 < m) p2n = Ppk[(size_t)e2_s[wave][i2 + 1] * 128 + 64 + lane];
            float x0 = p1lo + bf_lo(p2);
            float x1 = p1hi + bf_hi(p2);
            const float* afp = afw + i2 * 21;
#pragma unroll
            for (int k = 0; k < NB; ++k) {
                const float a = afp[k];
                const float2 w = w1c2[k * 64 + lane];
                x0 = fmaf(a, w.x, x0);
                x1 = fmaf(a, w.y, x1);
            }
            acc0 += silu_f(x0);
            acc1 += silu_f(x1);
        }
    }
    float2 o;
    o.x = acc0;
    o.y = acc1;
    ((float2*)S)[(size_t)e * 64 + lane] = o;
}

// ---------------------------------------------------------------------------
// kernel C: out = S @ M + cnt*cvec + bu, in-place on d_out. 4 edges / iter.
// ---------------------------------------------------------------------------
__global__ void __launch_bounds__(256) kC(const uint32_t* __restrict__ Mpk,
                                          const float* __restrict__ cvec,
                                          const float* __restrict__ bu,
                                          const uint32_t* __restrict__ cnt,
                                          float* __restrict__ S, int E) {
    __shared__ uint32_t M_s[128 * 64];
    __shared__ float s_s[4][128];
    const int tid = threadIdx.x;
    for (int i = tid; i < 8192; i += 256) M_s[i] = Mpk[i];

    const int sel = tid >> 6;
    const int q = tid & 63;
    const float cv0 = cvec[2 * q], cv1 = cvec[2 * q + 1];
    const float bu0 = bu[2 * q], bu1 = bu[2 * q + 1];

    const int ng = (E + 3) >> 2;
    for (int g = blockIdx.x; g < ng; g += gridDim.x) {
        const int ebase = g * 4;
        const int nrow = min(4, E - ebase) * 128;
        __syncthreads();
        for (int i = tid; i < nrow; i += 256) ((float*)s_s)[i] = S[(size_t)ebase * 128 + i];
        __syncthreads();
        const int e = ebase + sel;
        if (e < E) {
            const float fc = (float)cnt[e];
            float acc0 = fmaf(fc, cv0, bu0);
            float acc1 = fmaf(fc, cv1, bu1);
#pragma unroll 8
            for (int k = 0; k < 128; ++k) {
                uint32_t m = M_s[k * 64 + q];
                float s = s_s[sel][k];
                acc0 = fmaf(s, bf_lo(m), acc0);
                acc1 = fmaf(s, bf_hi(m), acc1);
            }
            float2 o;
            o.x = acc0;
            o.y = acc1;
            ((float2*)S)[(size_t)e * 64 + q] = o;
        }
    }
}

// ---------------------------------------------------------------------------
extern "C" void kernel_launch(void* const* d_in, const int* in_sizes, int n_in,
                              void* d_out, int out_size, void* d_ws, size_t ws_size,
                              hipStream_t stream) {
    const float* edge_attr = (const float*)d_in[0];
    // d_in[1]: three_body_indices — unused by the reference computation
    const int* tbe = (const int*)d_in[2];
    const float* evec = (const float*)d_in[3];
    const float* Wa1 = (const float*)d_in[4];
    const float* ba1 = (const float*)d_in[5];
    const float* Wa2 = (const float*)d_in[6];
    const float* ba2 = (const float*)d_in[7];
    const float* W1 = (const float*)d_in[8];
    const float* b1 = (const float*)d_in[9];
    const float* W2 = (const float*)d_in[10];
    const float* b2 = (const float*)d_in[11];
    const float* Wu = (const float*)d_in[12];
    const float* bu = (const float*)d_in[13];

    const int E = in_sizes[0] / 128;
    const int T = in_sizes[2] / 2;
    float* S = (float*)d_out;

    const int nScanBlk = (E + 255) / 256;   // 391 for E=1e5

    char* ws = (char*)d_ws;
    size_t off = 0;
    uint32_t* Ppk = (uint32_t*)(ws + off); off += (size_t)E * 512;   // bf16 E x 256
    uint32_t* cnt = (uint32_t*)(ws + off); off += (size_t)E * 4;
    uint32_t* offs = (uint32_t*)(ws + off); off += (size_t)E * 4;
    uint32_t* sorted = (uint32_t*)(ws + off); off += (size_t)T * 4;
    uint32_t* bsum = (uint32_t*)(ws + off); off += (size_t)((nScanBlk + 3) & ~3) * 4;
    uint32_t* Mpk = (uint32_t*)(ws + off); off += 32768;
    float* cvec = (float*)(ws + off); off += 512;

    hipMemsetAsync(cnt, 0, (size_t)E * 4, stream);

    prep_kernel<<<129, 64, 0, stream>>>(W2, b2, Wu, Mpk, cvec);
    kA<<<(E + 31) / 32, 256, 0, stream>>>(edge_attr, W1, (uint16_t*)Ppk, E);
    khist<<<2048, 256, 0, stream>>>(tbe, cnt, T);
    scanA<<<nScanBlk, 256, 0, stream>>>(cnt, bsum, E);
    scanB<<<1, 512, 0, stream>>>(bsum, nScanBlk);
    scanC<<<nScanBlk, 256, 0, stream>>>(cnt, bsum, offs, E);
    kscat<<<2048, 256, 0, stream>>>(tbe, offs, sorted, T);
    kB3<<<(E + 3) / 4, 256, 0, stream>>>(sorted, offs, evec, Wa1, ba1, Wa2, ba2,
                                         W1, b1, Ppk, S, E);
    kC<<<512, 256, 0, stream>>>(Mpk, cvec, bu, cnt, S, E);
}

// Round 3
// 731.478 us; speedup vs baseline: 1.7470x; 1.1107x over previous
//
#include <hip/hip_runtime.h>
#include <stdint.h>

#define NB 20

__device__ __forceinline__ float bf_lo(uint32_t u) { return __uint_as_float(u << 16); }
__device__ __forceinline__ float bf_hi(uint32_t u) { return __uint_as_float(u & 0xffff0000u); }
__device__ __forceinline__ uint32_t f2bf(float f) {
    uint32_t u = __float_as_uint(f);
    return (u + 0x7fffu + ((u >> 16) & 1u)) >> 16;  // RNE
}
__device__ __forceinline__ uint32_t pack_bf2(float a, float b) {
    return f2bf(a) | (f2bf(b) << 16);
}
// fast silu: x * rcp(1 + 2^(-x*log2e)); ~1ulp rcp/exp2, fine vs 0.15 abs threshold
__device__ __forceinline__ float silu_f(float x) {
    float e = __builtin_amdgcn_exp2f(-1.4426950408889634f * x);
    return x * __builtin_amdgcn_rcpf(1.f + e);
}

// ---------------------------------------------------------------------------
// prep: M = W2 @ Wu (packed bf16 pairs, [128][64] uints), cvec = b2 @ Wu (fp32)
// ---------------------------------------------------------------------------
__global__ void prep_kernel(const float* __restrict__ W2, const float* __restrict__ b2,
                            const float* __restrict__ Wu,
                            uint32_t* __restrict__ Mpk, float* __restrict__ cvec) {
    int q = threadIdx.x;           // 0..63 -> cols 2q, 2q+1
    int k = blockIdx.x;            // 0..127 rows of M; 128 -> cvec
    const float* row = (k < 128) ? (W2 + k * 128) : b2;
    float acc0 = 0.f, acc1 = 0.f;
    for (int j = 0; j < 128; ++j) {
        float w = row[j];
        float2 wu = *(const float2*)(Wu + j * 128 + 2 * q);
        acc0 = fmaf(w, wu.x, acc0);
        acc1 = fmaf(w, wu.y, acc1);
    }
    if (k < 128) {
        Mpk[k * 64 + q] = pack_bf2(acc0, acc1);
    } else {
        cvec[2 * q] = acc0;
        cvec[2 * q + 1] = acc1;
    }
}

// ---------------------------------------------------------------------------
// kernel A: P[e][0:256] bf16, P1 = edge_attr @ W1[0:128,:], P2 = @ W1[128:256,:]
// ---------------------------------------------------------------------------
__global__ void __launch_bounds__(256) kA(const float* __restrict__ edge_attr,
                                          const float* __restrict__ W1,
                                          uint16_t* __restrict__ Pb, int E) {
    __shared__ float a_lds[32 * 128];
    const int tid = threadIdx.x;
    const int e0 = blockIdx.x * 32;
    const int nE = min(32, E - e0);

    {
        const float4* src = (const float4*)(edge_attr + (size_t)e0 * 128);
        int lim = nE * 32;
        for (int idx = tid; idx < lim; idx += 256)
            ((float4*)a_lds)[idx] = src[idx];
    }
    __syncthreads();

    const int c = tid;
    const float* wp = (c < 128) ? (W1 + c) : (W1 + 128 * 128 + (c - 128));

    float acc[32];
#pragma unroll
    for (int e = 0; e < 32; ++e) acc[e] = 0.f;

    for (int k = 0; k < 128; k += 4) {
        float w0 = wp[(k + 0) * 128];
        float w1 = wp[(k + 1) * 128];
        float w2 = wp[(k + 2) * 128];
        float w3 = wp[(k + 3) * 128];
#pragma unroll
        for (int e = 0; e < 32; ++e) {
            float4 a = *(const float4*)(a_lds + e * 128 + k);
            acc[e] = fmaf(a.x, w0, acc[e]);
            acc[e] = fmaf(a.y, w1, acc[e]);
            acc[e] = fmaf(a.z, w2, acc[e]);
            acc[e] = fmaf(a.w, w3, acc[e]);
        }
    }
#pragma unroll
    for (int e = 0; e < 32; ++e) {
        if (e < nE) Pb[(size_t)(e0 + e) * 256 + c] = (uint16_t)f2bf(acc[e]);
    }
}

// ---------------------------------------------------------------------------
// counting sort by e_ij: hist -> scan (3 kernels) -> scatter of (e_ij,e_ik)
// ---------------------------------------------------------------------------
__global__ void khist(const int* __restrict__ tbe, uint32_t* __restrict__ cnt, int T) {
    int t = blockIdx.x * blockDim.x + threadIdx.x;
    int stride = gridDim.x * blockDim.x;
    for (; t < T; t += stride) {
        int2 ee = ((const int2*)tbe)[t];
        atomicAdd(&cnt[ee.x], 1u);
    }
}

__global__ void scanA(const uint32_t* __restrict__ cnt, uint32_t* __restrict__ bsum, int E) {
    __shared__ uint32_t s[256];
    int tid = threadIdx.x;
    int e = blockIdx.x * 256 + tid;
    s[tid] = (e < E) ? cnt[e] : 0u;
    __syncthreads();
    for (int off = 128; off > 0; off >>= 1) {
        if (tid < off) s[tid] += s[tid + off];
        __syncthreads();
    }
    if (tid == 0) bsum[blockIdx.x] = s[0];
}

__global__ void scanB(uint32_t* __restrict__ bsum, int n) {
    __shared__ uint32_t s[512];
    int tid = threadIdx.x;
    s[tid] = (tid < n) ? bsum[tid] : 0u;
    __syncthreads();
    for (int off = 1; off < 512; off <<= 1) {
        uint32_t a = (tid >= off) ? s[tid - off] : 0u;
        __syncthreads();
        s[tid] += a;
        __syncthreads();
    }
    if (tid < n) bsum[tid] = (tid > 0) ? s[tid - 1] : 0u;
}

__global__ void scanC(const uint32_t* __restrict__ cnt, const uint32_t* __restrict__ bsum,
                      uint32_t* __restrict__ offs, int E) {
    __shared__ uint32_t s[256];
    int tid = threadIdx.x;
    int e = blockIdx.x * 256 + tid;
    uint32_t v = (e < E) ? cnt[e] : 0u;
    s[tid] = v;
    __syncthreads();
    for (int off = 1; off < 256; off <<= 1) {
        uint32_t a = (tid >= off) ? s[tid - off] : 0u;
        __syncthreads();
        s[tid] += a;
        __syncthreads();
    }
    if (e < E) offs[e] = bsum[blockIdx.x] + s[tid] - v;   // exclusive start
}

__global__ void kscat(const int* __restrict__ tbe, uint32_t* __restrict__ offs,
                      uint2* __restrict__ sorted2, int T) {
    int t = blockIdx.x * blockDim.x + threadIdx.x;
    int stride = gridDim.x * blockDim.x;
    for (; t < T; t += stride) {
        int2 ee = ((const int2*)tbe)[t];
        uint32_t pos = atomicAdd(&offs[ee.x], 1u);   // post-scatter: offs[e] = segment END
        uint2 o;
        o.x = (uint32_t)ee.x;
        o.y = (uint32_t)ee.y;
        sorted2[pos] = o;
    }
}

// ---------------------------------------------------------------------------
// kAF: dense per-triplet angle MLP over the SORTED triplet list. Full lane
// utilization. Output af packed bf16 pairs: afpk[t][0..9] dwords.
// ---------------------------------------------------------------------------
__global__ void __launch_bounds__(256) kAF(const uint2* __restrict__ sorted2,
                                           const float* __restrict__ evec,
                                           const float* __restrict__ Wa1,
                                           const float* __restrict__ ba1,
                                           const float* __restrict__ Wa2,
                                           const float* __restrict__ ba2,
                                           uint32_t* __restrict__ afpk, int T) {
    __shared__ float wa1_s[60], ba1_s[NB], wa2_s[400], ba2_s[NB];
    const int tid = threadIdx.x;
    for (int i = tid; i < 400; i += 256) wa2_s[i] = Wa2[i];
    if (tid < 60) wa1_s[tid] = Wa1[tid];
    if (tid < NB) { ba1_s[tid] = ba1[tid]; ba2_s[tid] = ba2[tid]; }
    __syncthreads();

    const int t = blockIdx.x * 256 + tid;
    if (t >= T) return;

    uint2 ee = sorted2[t];
    const float ax = evec[ee.x * 3], ay = evec[ee.x * 3 + 1], az = evec[ee.x * 3 + 2];
    const float bx = evec[ee.y * 3], by = evec[ee.y * 3 + 1], bz = evec[ee.y * 3 + 2];
    const float li = fmaxf(__builtin_amdgcn_sqrtf(ax * ax + ay * ay + az * az), 1e-6f);
    const float lk = fmaxf(__builtin_amdgcn_sqrtf(bx * bx + by * by + bz * bz), 1e-6f);
    float ct = (ax * bx + ay * by + az * bz) * __builtin_amdgcn_rcpf(li * lk);
    ct = fminf(fmaxf(ct, -1.f), 1.f);

    float h[NB];
#pragma unroll
    for (int o = 0; o < NB; ++o) {
        float z = fmaf(li, wa1_s[o], fmaf(lk, wa1_s[20 + o], fmaf(ct, wa1_s[40 + o], ba1_s[o])));
        h[o] = silu_f(z);
    }
    float af[NB];
#pragma unroll
    for (int o2 = 0; o2 < NB; ++o2) af[o2] = ba2_s[o2];
#pragma unroll
    for (int o = 0; o < NB; ++o) {
#pragma unroll
        for (int o2 = 0; o2 < NB; ++o2) af[o2] = fmaf(h[o], wa2_s[o * 20 + o2], af[o2]);
    }
    uint32_t* dst = afpk + (size_t)t * 10;
#pragma unroll
    for (int j = 0; j < 5; ++j) {
        uint2 pk;
        pk.x = pack_bf2(af[4 * j], af[4 * j + 1]);
        pk.y = pack_bf2(af[4 * j + 2], af[4 * j + 3]);
        *(uint2*)(dst + 2 * j) = pk;   // t*40B: 8B-aligned
    }
}

// ---------------------------------------------------------------------------
// kernel B4: one wave per edge. W1c in VGPRs, af broadcast from LDS,
// accumulate silu(pre) in registers, write S row once. No atomics.
// ---------------------------------------------------------------------------
__global__ void __launch_bounds__(256) kB4(const uint2* __restrict__ sorted2,
                                           const uint32_t* __restrict__ offs,
                                           const float* __restrict__ W1,
                                           const float* __restrict__ b1,
                                           const uint32_t* __restrict__ Ppk,
                                           const uint32_t* __restrict__ afpk,
                                           float* __restrict__ S, int E) {
    __shared__ float w1c_s[NB * 128];      // W1 rows 256..275
    __shared__ uint32_t af_s[4][64 * 10];  // per-wave af staging (bf16 pairs)
    __shared__ uint32_t e2_s[4][64];

    const int tid = threadIdx.x;
    for (int i = tid; i < NB * 128; i += 256) w1c_s[i] = W1[256 * 128 + i];
    __syncthreads();

    const int wave = tid >> 6, lane = tid & 63;
    const int e = blockIdx.x * 4 + wave;
    if (e >= E) return;   // no block barriers below — safe divergence

    // hoist W1c fragment into 40 VGPRs
    const float2* w1c2 = (const float2*)w1c_s;
    float2 wreg[NB];
#pragma unroll
    for (int k = 0; k < NB; ++k) wreg[k] = w1c2[k * 64 + lane];

    const uint32_t start = (e > 0) ? offs[e - 1] : 0u;
    const uint32_t end = offs[e];
    const int n = (int)(end - start);

    const float2 b1v = ((const float2*)b1)[lane];
    const uint32_t p1 = Ppk[(size_t)e * 128 + lane];
    const float p1lo = bf_lo(p1) + b1v.x;
    const float p1hi = bf_hi(p1) + b1v.y;
    float acc0 = 0.f, acc1 = 0.f;

    uint32_t* afw = af_s[wave];

    for (int c0 = 0; c0 < n; c0 += 64) {
        const int m = min(64, n - c0);
        // stage af rows (coalesced) + e2 list for this chunk
        const uint32_t base10 = (start + c0) * 10u;
        for (int i = lane; i < m * 10; i += 64) afw[i] = afpk[base10 + i];
        if (lane < m) e2_s[wave][lane] = sorted2[start + c0 + lane].y;
        // within-wave LDS producer->consumer: drain ds_writes, pin ordering
        asm volatile("s_waitcnt lgkmcnt(0)" ::: "memory");
        __builtin_amdgcn_sched_barrier(0);

        uint32_t p2n = Ppk[(size_t)e2_s[wave][0] * 128 + 64 + lane];
        for (int i2 = 0; i2 < m; ++i2) {
            const uint32_t p2 = p2n;
            if (i2 + 1 < m) p2n = Ppk[(size_t)e2_s[wave][i2 + 1] * 128 + 64 + lane];
            float x0 = p1lo + bf_lo(p2);
            float x1 = p1hi + bf_hi(p2);
            const uint32_t* afp = afw + i2 * 10;
#pragma unroll
            for (int j = 0; j < 10; ++j) {
                const uint32_t u = afp[j];       // lane-uniform broadcast
                const float a0 = bf_lo(u), a1 = bf_hi(u);
                x0 = fmaf(a0, wreg[2 * j].x, x0);
                x1 = fmaf(a0, wreg[2 * j].y, x1);
                x0 = fmaf(a1, wreg[2 * j + 1].x, x0);
                x1 = fmaf(a1, wreg[2 * j + 1].y, x1);
            }
            acc0 += silu_f(x0);
            acc1 += silu_f(x1);
        }
    }
    float2 o;
    o.x = acc0;
    o.y = acc1;
    ((float2*)S)[(size_t)e * 64 + lane] = o;
}

// ---------------------------------------------------------------------------
// kernel C: out = S @ M + cnt*cvec + bu, in-place on d_out. 4 edges / iter.
// ---------------------------------------------------------------------------
__global__ void __launch_bounds__(256) kC(const uint32_t* __restrict__ Mpk,
                                          const float* __restrict__ cvec,
                                          const float* __restrict__ bu,
                                          const uint32_t* __restrict__ cnt,
                                          float* __restrict__ S, int E) {
    __shared__ uint32_t M_s[128 * 64];
    __shared__ float s_s[4][128];
    const int tid = threadIdx.x;
    for (int i = tid; i < 8192; i += 256) M_s[i] = Mpk[i];

    const int sel = tid >> 6;
    const int q = tid & 63;
    const float cv0 = cvec[2 * q], cv1 = cvec[2 * q + 1];
    const float bu0 = bu[2 * q], bu1 = bu[2 * q + 1];

    const int ng = (E + 3) >> 2;
    for (int g = blockIdx.x; g < ng; g += gridDim.x) {
        const int ebase = g * 4;
        const int nrow = min(4, E - ebase) * 128;
        __syncthreads();
        for (int i = tid; i < nrow; i += 256) ((float*)s_s)[i] = S[(size_t)ebase * 128 + i];
        __syncthreads();
        const int e = ebase + sel;
        if (e < E) {
            const float fc = (float)cnt[e];
            float acc0 = fmaf(fc, cv0, bu0);
            float acc1 = fmaf(fc, cv1, bu1);
#pragma unroll 8
            for (int k = 0; k < 128; ++k) {
                uint32_t m = M_s[k * 64 + q];
                float s = s_s[sel][k];
                acc0 = fmaf(s, bf_lo(m), acc0);
                acc1 = fmaf(s, bf_hi(m), acc1);
            }
            float2 o;
            o.x = acc0;
            o.y = acc1;
            ((float2*)S)[(size_t)e * 64 + q] = o;
        }
    }
}

// ---------------------------------------------------------------------------
extern "C" void kernel_launch(void* const* d_in, const int* in_sizes, int n_in,
                              void* d_out, int out_size, void* d_ws, size_t ws_size,
                              hipStream_t stream) {
    const float* edge_attr = (const float*)d_in[0];
    // d_in[1]: three_body_indices — unused by the reference computation
    const int* tbe = (const int*)d_in[2];
    const float* evec = (const float*)d_in[3];
    const float* Wa1 = (const float*)d_in[4];
    const float* ba1 = (const float*)d_in[5];
    const float* Wa2 = (const float*)d_in[6];
    const float* ba2 = (const float*)d_in[7];
    const float* W1 = (const float*)d_in[8];
    const float* b1 = (const float*)d_in[9];
    const float* W2 = (const float*)d_in[10];
    const float* b2 = (const float*)d_in[11];
    const float* Wu = (const float*)d_in[12];
    const float* bu = (const float*)d_in[13];

    const int E = in_sizes[0] / 128;
    const int T = in_sizes[2] / 2;
    float* S = (float*)d_out;

    const int nScanBlk = (E + 255) / 256;   // 391 for E=1e5

    char* ws = (char*)d_ws;
    size_t off = 0;
    uint32_t* Ppk = (uint32_t*)(ws + off); off += (size_t)E * 512;   // bf16 E x 256
    uint32_t* cnt = (uint32_t*)(ws + off); off += (size_t)E * 4;
    uint32_t* offs = (uint32_t*)(ws + off); off += (size_t)E * 4;
    uint2* sorted2 = (uint2*)(ws + off); off += (size_t)T * 8;
    uint32_t* afpk = (uint32_t*)(ws + off); off += (size_t)T * 40;
    uint32_t* bsum = (uint32_t*)(ws + off); off += (size_t)((nScanBlk + 3) & ~3) * 4;
    uint32_t* Mpk = (uint32_t*)(ws + off); off += 32768;
    float* cvec = (float*)(ws + off); off += 512;

    hipMemsetAsync(cnt, 0, (size_t)E * 4, stream);

    prep_kernel<<<129, 64, 0, stream>>>(W2, b2, Wu, Mpk, cvec);
    kA<<<(E + 31) / 32, 256, 0, stream>>>(edge_attr, W1, (uint16_t*)Ppk, E);
    khist<<<2048, 256, 0, stream>>>(tbe, cnt, T);
    scanA<<<nScanBlk, 256, 0, stream>>>(cnt, bsum, E);
    scanB<<<1, 512, 0, stream>>>(bsum, nScanBlk);
    scanC<<<nScanBlk, 256, 0, stream>>>(cnt, bsum, offs, E);
    kscat<<<2048, 256, 0, stream>>>(tbe, offs, sorted2, T);
    kAF<<<(T + 255) / 256, 256, 0, stream>>>(sorted2, evec, Wa1, ba1, Wa2, ba2, afpk, T);
    kB4<<<(E + 3) / 4, 256, 0, stream>>>(sorted2, offs, W1, b1, Ppk, afpk, S, E);
    kC<<<512, 256, 0, stream>>>(Mpk, cvec, bu, cnt, S, E);
}

// Round 4
// 692.170 us; speedup vs baseline: 1.8462x; 1.0568x over previous
//
#include <hip/hip_runtime.h>
#include <stdint.h>

#define NB 20

__device__ __forceinline__ float bf_lo(uint32_t u) { return __uint_as_float(u << 16); }
__device__ __forceinline__ float bf_hi(uint32_t u) { return __uint_as_float(u & 0xffff0000u); }
__device__ __forceinline__ uint32_t f2bf(float f) {
    uint32_t u = __float_as_uint(f);
    return (u + 0x7fffu + ((u >> 16) & 1u)) >> 16;  // RNE
}
__device__ __forceinline__ uint32_t pack_bf2(float a, float b) {
    return f2bf(a) | (f2bf(b) << 16);
}
// fast silu: x * rcp(1 + 2^(-x*log2e)); ~1ulp rcp/exp2, fine vs 0.15 abs threshold
__device__ __forceinline__ float silu_f(float x) {
    float e = __builtin_amdgcn_exp2f(-1.4426950408889634f * x);
    return x * __builtin_amdgcn_rcpf(1.f + e);
}

// ---------------------------------------------------------------------------
// prep: M = W2 @ Wu (packed bf16 pairs, [128][64] uints), cvec = b2 @ Wu (fp32)
// ---------------------------------------------------------------------------
__global__ void prep_kernel(const float* __restrict__ W2, const float* __restrict__ b2,
                            const float* __restrict__ Wu,
                            uint32_t* __restrict__ Mpk, float* __restrict__ cvec) {
    int q = threadIdx.x;           // 0..63 -> cols 2q, 2q+1
    int k = blockIdx.x;            // 0..127 rows of M; 128 -> cvec
    const float* row = (k < 128) ? (W2 + k * 128) : b2;
    float acc0 = 0.f, acc1 = 0.f;
    for (int j = 0; j < 128; ++j) {
        float w = row[j];
        float2 wu = *(const float2*)(Wu + j * 128 + 2 * q);
        acc0 = fmaf(w, wu.x, acc0);
        acc1 = fmaf(w, wu.y, acc1);
    }
    if (k < 128) {
        Mpk[k * 64 + q] = pack_bf2(acc0, acc1);
    } else {
        cvec[2 * q] = acc0;
        cvec[2 * q + 1] = acc1;
    }
}

// ---------------------------------------------------------------------------
// kernel A2: P[e][0:256] bf16. Thread owns cols (c, c+128) which share the
// same A row data -> one ds_read_b128 feeds 8 FMAs (was 4). FMA-bound now.
// ---------------------------------------------------------------------------
__global__ void __launch_bounds__(256) kA2(const float* __restrict__ edge_attr,
                                           const float* __restrict__ W1,
                                           uint16_t* __restrict__ Pb, int E) {
    __shared__ float a_lds[32 * 128];
    const int tid = threadIdx.x;
    const int e0 = blockIdx.x * 32;
    const int nE = min(32, E - e0);

    {
        const float4* src = (const float4*)(edge_attr + (size_t)e0 * 128);
        int lim = nE * 32;
        for (int idx = tid; idx < lim; idx += 256)
            ((float4*)a_lds)[idx] = src[idx];
    }
    __syncthreads();

    const int c = tid & 127;        // column within each 128-half
    const int eh = tid >> 7;        // edge half: 0 -> edges 0..15, 1 -> 16..31
    const float* wp1 = W1 + c;                    // W1[k][c]
    const float* wp2 = W1 + 128 * 128 + c;        // W1[128+k][c]

    float acc0[16], acc1[16];
#pragma unroll
    for (int e = 0; e < 16; ++e) { acc0[e] = 0.f; acc1[e] = 0.f; }

    const float* abase = a_lds + eh * 16 * 128;
    for (int k = 0; k < 128; k += 4) {
        float w10 = wp1[(k + 0) * 128], w11 = wp1[(k + 1) * 128];
        float w12 = wp1[(k + 2) * 128], w13 = wp1[(k + 3) * 128];
        float w20 = wp2[(k + 0) * 128], w21 = wp2[(k + 1) * 128];
        float w22 = wp2[(k + 2) * 128], w23 = wp2[(k + 3) * 128];
#pragma unroll
        for (int e = 0; e < 16; ++e) {
            float4 a = *(const float4*)(abase + e * 128 + k);
            acc0[e] = fmaf(a.x, w10, acc0[e]);
            acc0[e] = fmaf(a.y, w11, acc0[e]);
            acc0[e] = fmaf(a.z, w12, acc0[e]);
            acc0[e] = fmaf(a.w, w13, acc0[e]);
            acc1[e] = fmaf(a.x, w20, acc1[e]);
            acc1[e] = fmaf(a.y, w21, acc1[e]);
            acc1[e] = fmaf(a.z, w22, acc1[e]);
            acc1[e] = fmaf(a.w, w23, acc1[e]);
        }
    }
#pragma unroll
    for (int e = 0; e < 16; ++e) {
        const int ge = eh * 16 + e;
        if (ge < nE) {
            uint16_t* dst = Pb + (size_t)(e0 + ge) * 256;
            dst[c] = (uint16_t)f2bf(acc0[e]);
            dst[c + 128] = (uint16_t)f2bf(acc1[e]);
        }
    }
}

// ---------------------------------------------------------------------------
// counting sort by e_ij: hist -> scan (3 kernels); scatter fused into kSA
// ---------------------------------------------------------------------------
__global__ void khist(const int* __restrict__ tbe, uint32_t* __restrict__ cnt, int T) {
    int t = blockIdx.x * blockDim.x + threadIdx.x;
    int stride = gridDim.x * blockDim.x;
    for (; t < T; t += stride) {
        int2 ee = ((const int2*)tbe)[t];
        atomicAdd(&cnt[ee.x], 1u);
    }
}

__global__ void scanA(const uint32_t* __restrict__ cnt, uint32_t* __restrict__ bsum, int E) {
    __shared__ uint32_t s[256];
    int tid = threadIdx.x;
    int e = blockIdx.x * 256 + tid;
    s[tid] = (e < E) ? cnt[e] : 0u;
    __syncthreads();
    for (int off = 128; off > 0; off >>= 1) {
        if (tid < off) s[tid] += s[tid + off];
        __syncthreads();
    }
    if (tid == 0) bsum[blockIdx.x] = s[0];
}

__global__ void scanB(uint32_t* __restrict__ bsum, int n) {
    __shared__ uint32_t s[512];
    int tid = threadIdx.x;
    s[tid] = (tid < n) ? bsum[tid] : 0u;
    __syncthreads();
    for (int off = 1; off < 512; off <<= 1) {
        uint32_t a = (tid >= off) ? s[tid - off] : 0u;
        __syncthreads();
        s[tid] += a;
        __syncthreads();
    }
    if (tid < n) bsum[tid] = (tid > 0) ? s[tid - 1] : 0u;
}

__global__ void scanC(const uint32_t* __restrict__ cnt, const uint32_t* __restrict__ bsum,
                      uint32_t* __restrict__ offs, int E) {
    __shared__ uint32_t s[256];
    int tid = threadIdx.x;
    int e = blockIdx.x * 256 + tid;
    uint32_t v = (e < E) ? cnt[e] : 0u;
    s[tid] = v;
    __syncthreads();
    for (int off = 1; off < 256; off <<= 1) {
        uint32_t a = (tid >= off) ? s[tid - off] : 0u;
        __syncthreads();
        s[tid] += a;
        __syncthreads();
    }
    if (e < E) offs[e] = bsum[blockIdx.x] + s[tid] - v;   // exclusive start
}

// ---------------------------------------------------------------------------
// kSA: fused scatter + angle MLP. Dense over the UNSORTED triplet list at
// full lane utilization; writes af (bf16 pairs) and e2 at the sorted position.
// After this kernel offs[e] = segment END.
// ---------------------------------------------------------------------------
__global__ void __launch_bounds__(256) kSA(const int* __restrict__ tbe,
                                           const float* __restrict__ evec,
                                           const float* __restrict__ Wa1,
                                           const float* __restrict__ ba1,
                                           const float* __restrict__ Wa2,
                                           const float* __restrict__ ba2,
                                           uint32_t* __restrict__ offs,
                                           uint32_t* __restrict__ afpk,
                                           uint32_t* __restrict__ sortedE2, int T) {
    __shared__ float wa1_s[60], ba1_s[NB], wa2_s[400], ba2_s[NB];
    const int tid = threadIdx.x;
    for (int i = tid; i < 400; i += 256) wa2_s[i] = Wa2[i];
    if (tid < 60) wa1_s[tid] = Wa1[tid];
    if (tid < NB) { ba1_s[tid] = ba1[tid]; ba2_s[tid] = ba2[tid]; }
    __syncthreads();

    const int t = blockIdx.x * 256 + tid;
    if (t >= T) return;

    int2 ee = ((const int2*)tbe)[t];
    const float ax = evec[ee.x * 3], ay = evec[ee.x * 3 + 1], az = evec[ee.x * 3 + 2];
    const float bx = evec[ee.y * 3], by = evec[ee.y * 3 + 1], bz = evec[ee.y * 3 + 2];
    const float li = fmaxf(__builtin_amdgcn_sqrtf(ax * ax + ay * ay + az * az), 1e-6f);
    const float lk = fmaxf(__builtin_amdgcn_sqrtf(bx * bx + by * by + bz * bz), 1e-6f);
    float ct = (ax * bx + ay * by + az * bz) * __builtin_amdgcn_rcpf(li * lk);
    ct = fminf(fmaxf(ct, -1.f), 1.f);

    float h[NB];
#pragma unroll
    for (int o = 0; o < NB; ++o) {
        float z = fmaf(li, wa1_s[o], fmaf(lk, wa1_s[20 + o], fmaf(ct, wa1_s[40 + o], ba1_s[o])));
        h[o] = silu_f(z);
    }
    float af[NB];
#pragma unroll
    for (int o2 = 0; o2 < NB; ++o2) af[o2] = ba2_s[o2];
#pragma unroll
    for (int o = 0; o < NB; ++o) {
#pragma unroll
        for (int o2 = 0; o2 < NB; ++o2) af[o2] = fmaf(h[o], wa2_s[o * 20 + o2], af[o2]);
    }

    const uint32_t pos = atomicAdd(&offs[ee.x], 1u);
    sortedE2[pos] = (uint32_t)ee.y;
    uint32_t* dst = afpk + (size_t)pos * 10;
#pragma unroll
    for (int j = 0; j < 5; ++j) {
        uint2 pk;
        pk.x = pack_bf2(af[4 * j], af[4 * j + 1]);
        pk.y = pack_bf2(af[4 * j + 2], af[4 * j + 3]);
        *(uint2*)(dst + 2 * j) = pk;   // pos*40B: 8B-aligned
    }
}

// ---------------------------------------------------------------------------
// kernel B4: one wave per edge. W1c in VGPRs, af broadcast from LDS (rows
// padded to 12 dwords -> b128/b64 reads), 2-deep p2 prefetch. No atomics.
// ---------------------------------------------------------------------------
__global__ void __launch_bounds__(256) kB4(const uint32_t* __restrict__ sortedE2,
                                           const uint32_t* __restrict__ offs,
                                           const float* __restrict__ W1,
                                           const float* __restrict__ b1,
                                           const uint32_t* __restrict__ Ppk,
                                           const uint32_t* __restrict__ afpk,
                                           float* __restrict__ S, int E) {
    __shared__ float w1c_s[NB * 128];      // W1 rows 256..275
    __shared__ uint32_t af_s[4][64 * 12];  // per-wave af staging, 16B-aligned rows
    __shared__ uint32_t e2_s[4][64];

    const int tid = threadIdx.x;
    for (int i = tid; i < NB * 128; i += 256) w1c_s[i] = W1[256 * 128 + i];
    __syncthreads();

    const int wave = tid >> 6, lane = tid & 63;
    const int e = blockIdx.x * 4 + wave;
    if (e >= E) return;   // no block barriers below — safe divergence

    // hoist W1c fragment into 40 VGPRs
    const float2* w1c2 = (const float2*)w1c_s;
    float2 wreg[NB];
#pragma unroll
    for (int k = 0; k < NB; ++k) wreg[k] = w1c2[k * 64 + lane];

    const uint32_t start = (e > 0) ? offs[e - 1] : 0u;
    const uint32_t end = offs[e];
    const int n = (int)(end - start);

    const float2 b1v = ((const float2*)b1)[lane];
    const uint32_t p1 = Ppk[(size_t)e * 128 + lane];
    const float p1lo = bf_lo(p1) + b1v.x;
    const float p1hi = bf_hi(p1) + b1v.y;
    float acc0 = 0.f, acc1 = 0.f;

    uint32_t* afw = af_s[wave];

    for (int c0 = 0; c0 < n; c0 += 64) {
        const int m = min(64, n - c0);
        // stage af rows (coalesced global; LDS stride 12) + e2 list
        const uint32_t base10 = (start + c0) * 10u;
        for (int i = lane; i < m * 10; i += 64) {
            int r = i / 10;
            afw[r * 12 + (i - r * 10)] = afpk[base10 + i];
        }
        if (lane < m) e2_s[wave][lane] = sortedE2[start + c0 + lane];
        // within-wave LDS producer->consumer: drain ds_writes, pin ordering
        asm volatile("s_waitcnt lgkmcnt(0)" ::: "memory");
        __builtin_amdgcn_sched_barrier(0);

        // 2-deep p2 prefetch pipeline
        uint32_t p2a = Ppk[(size_t)e2_s[wave][0] * 128 + 64 + lane];
        uint32_t p2b = (m > 1) ? Ppk[(size_t)e2_s[wave][1] * 128 + 64 + lane] : p2a;
        for (int i2 = 0; i2 < m; ++i2) {
            const uint32_t p2 = p2a;
            p2a = p2b;
            if (i2 + 2 < m) p2b = Ppk[(size_t)e2_s[wave][i2 + 2] * 128 + 64 + lane];
            float x0 = p1lo + bf_lo(p2);
            float x1 = p1hi + bf_hi(p2);
            const uint32_t* afp = afw + i2 * 12;
            const uint4 fA = *(const uint4*)(afp);
            const uint4 fB = *(const uint4*)(afp + 4);
            const uint2 fC = *(const uint2*)(afp + 8);
            const uint32_t aw[10] = {fA.x, fA.y, fA.z, fA.w, fB.x, fB.y, fB.z, fB.w, fC.x, fC.y};
#pragma unroll
            for (int j = 0; j < 10; ++j) {
                const uint32_t u = aw[j];        // lane-uniform
                const float a0 = bf_lo(u), a1 = bf_hi(u);
                x0 = fmaf(a0, wreg[2 * j].x, x0);
                x1 = fmaf(a0, wreg[2 * j].y, x1);
                x0 = fmaf(a1, wreg[2 * j + 1].x, x0);
                x1 = fmaf(a1, wreg[2 * j + 1].y, x1);
            }
            acc0 += silu_f(x0);
            acc1 += silu_f(x1);
        }
    }
    float2 o;
    o.x = acc0;
    o.y = acc1;
    ((float2*)S)[(size_t)e * 64 + lane] = o;
}

// ---------------------------------------------------------------------------
// kernel C: out = S @ M + cnt*cvec + bu, in-place on d_out. 4 edges / iter.
// ---------------------------------------------------------------------------
__global__ void __launch_bounds__(256) kC(const uint32_t* __restrict__ Mpk,
                                          const float* __restrict__ cvec,
                                          const float* __restrict__ bu,
                                          const uint32_t* __restrict__ cnt,
                                          float* __restrict__ S, int E) {
    __shared__ uint32_t M_s[128 * 64];
    __shared__ float s_s[4][128];
    const int tid = threadIdx.x;
    for (int i = tid; i < 8192; i += 256) M_s[i] = Mpk[i];

    const int sel = tid >> 6;
    const int q = tid & 63;
    const float cv0 = cvec[2 * q], cv1 = cvec[2 * q + 1];
    const float bu0 = bu[2 * q], bu1 = bu[2 * q + 1];

    const int ng = (E + 3) >> 2;
    for (int g = blockIdx.x; g < ng; g += gridDim.x) {
        const int ebase = g * 4;
        const int nrow = min(4, E - ebase) * 128;
        __syncthreads();
        for (int i = tid; i < nrow; i += 256) ((float*)s_s)[i] = S[(size_t)ebase * 128 + i];
        __syncthreads();
        const int e = ebase + sel;
        if (e < E) {
            const float fc = (float)cnt[e];
            float acc0 = fmaf(fc, cv0, bu0);
            float acc1 = fmaf(fc, cv1, bu1);
#pragma unroll 8
            for (int k = 0; k < 128; ++k) {
                uint32_t m = M_s[k * 64 + q];
                float s = s_s[sel][k];
                acc0 = fmaf(s, bf_lo(m), acc0);
                acc1 = fmaf(s, bf_hi(m), acc1);
            }
            float2 o;
            o.x = acc0;
            o.y = acc1;
            ((float2*)S)[(size_t)e * 64 + q] = o;
        }
    }
}

// ---------------------------------------------------------------------------
extern "C" void kernel_launch(void* const* d_in, const int* in_sizes, int n_in,
                              void* d_out, int out_size, void* d_ws, size_t ws_size,
                              hipStream_t stream) {
    const float* edge_attr = (const float*)d_in[0];
    // d_in[1]: three_body_indices — unused by the reference computation
    const int* tbe = (const int*)d_in[2];
    const float* evec = (const float*)d_in[3];
    const float* Wa1 = (const float*)d_in[4];
    const float* ba1 = (const float*)d_in[5];
    const float* Wa2 = (const float*)d_in[6];
    const float* ba2 = (const float*)d_in[7];
    const float* W1 = (const float*)d_in[8];
    const float* b1 = (const float*)d_in[9];
    const float* W2 = (const float*)d_in[10];
    const float* b2 = (const float*)d_in[11];
    const float* Wu = (const float*)d_in[12];
    const float* bu = (const float*)d_in[13];

    const int E = in_sizes[0] / 128;
    const int T = in_sizes[2] / 2;
    float* S = (float*)d_out;

    const int nScanBlk = (E + 255) / 256;   // 391 for E=1e5

    char* ws = (char*)d_ws;
    size_t off = 0;
    uint32_t* Ppk = (uint32_t*)(ws + off); off += (size_t)E * 512;   // bf16 E x 256
    uint32_t* cnt = (uint32_t*)(ws + off); off += (size_t)E * 4;
    uint32_t* offs = (uint32_t*)(ws + off); off += (size_t)E * 4;
    uint32_t* sortedE2 = (uint32_t*)(ws + off); off += (size_t)T * 4;
    uint32_t* afpk = (uint32_t*)(ws + off); off += (size_t)T * 40;
    uint32_t* bsum = (uint32_t*)(ws + off); off += (size_t)((nScanBlk + 3) & ~3) * 4;
    uint32_t* Mpk = (uint32_t*)(ws + off); off += 32768;
    float* cvec = (float*)(ws + off); off += 512;

    hipMemsetAsync(cnt, 0, (size_t)E * 4, stream);

    prep_kernel<<<129, 64, 0, stream>>>(W2, b2, Wu, Mpk, cvec);
    kA2<<<(E + 31) / 32, 256, 0, stream>>>(edge_attr, W1, (uint16_t*)Ppk, E);
    khist<<<2048, 256, 0, stream>>>(tbe, cnt, T);
    scanA<<<nScanBlk, 256, 0, stream>>>(cnt, bsum, E);
    scanB<<<1, 512, 0, stream>>>(bsum, nScanBlk);
    scanC<<<nScanBlk, 256, 0, stream>>>(cnt, bsum, offs, E);
    kSA<<<(T + 255) / 256, 256, 0, stream>>>(tbe, evec, Wa1, ba1, Wa2, ba2,
                                             offs, afpk, sortedE2, T);
    kB4<<<(E + 3) / 4, 256, 0, stream>>>(sortedE2, offs, W1, b1, Ppk, afpk, S, E);
    kC<<<1024, 256, 0, stream>>>(Mpk, cvec, bu, cnt, S, E);
}

// Round 6
// 518.530 us; speedup vs baseline: 2.4645x; 1.3349x over previous
//
#include <hip/hip_runtime.h>
#include <stdint.h>

#define NB 20

typedef __attribute__((ext_vector_type(8))) short bf16x8;
typedef __attribute__((ext_vector_type(4))) float f32x4;

__device__ __forceinline__ float bf_lo(uint32_t u) { return __uint_as_float(u << 16); }
__device__ __forceinline__ float bf_hi(uint32_t u) { return __uint_as_float(u & 0xffff0000u); }
__device__ __forceinline__ uint32_t f2bf(float f) {
    uint32_t u = __float_as_uint(f);
    return (u + 0x7fffu + ((u >> 16) & 1u)) >> 16;  // RNE
}
__device__ __forceinline__ uint32_t pack_bf2(float a, float b) {
    return f2bf(a) | (f2bf(b) << 16);
}
// fast silu: x * rcp(1 + 2^(-x*log2e))
__device__ __forceinline__ float silu_f(float x) {
    float e = __builtin_amdgcn_exp2f(-1.4426950408889634f * x);
    return x * __builtin_amdgcn_rcpf(1.f + e);
}

// ---------------------------------------------------------------------------
// prep: Mf32 = W2 @ Wu (fp32 [128][128]), cvec = b2 @ Wu (fp32). grid 129x64
// ---------------------------------------------------------------------------
__global__ void prep_kernel(const float* __restrict__ W2, const float* __restrict__ b2,
                            const float* __restrict__ Wu,
                            float* __restrict__ Mf32, float* __restrict__ cvec) {
    int q = threadIdx.x;           // cols 2q, 2q+1
    int k = blockIdx.x;            // 0..127 rows; 128 -> cvec
    const float* row = (k < 128) ? (W2 + k * 128) : b2;
    float acc0 = 0.f, acc1 = 0.f;
    for (int j = 0; j < 128; ++j) {
        float w = row[j];
        float2 wu = *(const float2*)(Wu + j * 128 + 2 * q);
        acc0 = fmaf(w, wu.x, acc0);
        acc1 = fmaf(w, wu.y, acc1);
    }
    if (k < 128) {
        Mf32[k * 128 + 2 * q] = acc0;
        Mf32[k * 128 + 2 * q + 1] = acc1;
    } else {
        cvec[2 * q] = acc0;
        cvec[2 * q + 1] = acc1;
    }
}

// ---------------------------------------------------------------------------
// prep2: W1[0:256] -> bf16 B-fragments for kA3. 16384 dwords.
// Layout: dword d = ((s*16+c)*64+l)*4+q holds B[k][col],B[k+1][col] with
// k = 32s+(l>>4)*8+2q, col = 16c+(l&15); Bcat col<128 -> W1 rows 0..127.
// ---------------------------------------------------------------------------
__global__ void prep2(const float* __restrict__ W1, uint32_t* __restrict__ Bpk) {
    int d = blockIdx.x * 256 + threadIdx.x;   // 0..16383
    int q = d & 3, l = (d >> 2) & 63, c = (d >> 8) & 15, s = d >> 12;
    int k = 32 * s + ((l >> 4) << 3) + (q << 1);
    int col = (c << 4) + (l & 15);
    int r0 = (col < 128) ? k : (k + 128);
    int cc = col & 127;
    float v0 = W1[(size_t)r0 * 128 + cc];
    float v1 = W1[(size_t)(r0 + 1) * 128 + cc];
    Bpk[d] = pack_bf2(v0, v1);
}

// prepM: Mf32 -> bf16 B-fragments for kC2 (N=128: c 0..7). 8192 dwords.
__global__ void prepM(const float* __restrict__ Mf32, uint32_t* __restrict__ Mfrag) {
    int d = blockIdx.x * 256 + threadIdx.x;   // 0..8191
    int q = d & 3, l = (d >> 2) & 63, c = (d >> 8) & 7, s = d >> 11;
    int k = 32 * s + ((l >> 4) << 3) + (q << 1);
    int col = (c << 4) + (l & 15);
    Mfrag[d] = pack_bf2(Mf32[k * 128 + col], Mf32[(k + 1) * 128 + col]);
}

// ---------------------------------------------------------------------------
// kA3: MFMA GEMM P = edge_attr (E x 128) @ Bcat (128 x 256), bf16 out.
// Block: 64 rows x 256 cols, 4 waves; wave w owns cols 64w..64w+63.
// A LDS: [row][k] bf16 with granule-XOR swizzle (g^=row&7) -> conflict-free.
// ---------------------------------------------------------------------------
__global__ void __launch_bounds__(256) kA3(const float* __restrict__ edge_attr,
                                           const uint32_t* __restrict__ Bpk,
                                           uint16_t* __restrict__ Pb, int E) {
    __shared__ uint32_t As[4096];    // 64 rows x 64 dwords (16KB)
    __shared__ uint32_t Bs[16384];   // 64KB fragment-ordered B
    const int tid = threadIdx.x;
    const int e0 = blockIdx.x * 64;
    const int nE = min(64, E - e0);

    for (int d = tid; d < 4096; d += 256) {
        int row = d >> 6, p = d & 63;
        int g = p >> 2;
        float2 v;
        if (row < nE) v = *(const float2*)(edge_attr + (size_t)(e0 + row) * 128 + 2 * p);
        else { v.x = 0.f; v.y = 0.f; }
        As[row * 64 + ((g ^ (row & 7)) << 2) + (p & 3)] = pack_bf2(v.x, v.y);
    }
    for (int d = tid; d < 4096; d += 256)
        ((uint4*)Bs)[d] = ((const uint4*)Bpk)[d];
    __syncthreads();

    const int w = tid >> 6, l = tid & 63;

    bf16x8 afr[4][4];   // [rb][s]
#pragma unroll
    for (int rb = 0; rb < 4; ++rb)
#pragma unroll
        for (int s = 0; s < 4; ++s) {
            int row = rb * 16 + (l & 15);
            int g = s * 4 + (l >> 4);
            afr[rb][s] = *(const bf16x8*)((const char*)As + row * 256 + ((g ^ (row & 7)) << 4));
        }

    f32x4 acc[4][4];    // [cl][rb]
#pragma unroll
    for (int cl = 0; cl < 4; ++cl)
#pragma unroll
        for (int rb = 0; rb < 4; ++rb) acc[cl][rb] = (f32x4)(0.f);

#pragma unroll
    for (int cl = 0; cl < 4; ++cl) {
        const int c = w * 4 + cl;
#pragma unroll
        for (int s = 0; s < 4; ++s) {
            bf16x8 bfr = *(const bf16x8*)((const char*)Bs + (((s * 16 + c) * 64 + l) << 4));
#pragma unroll
            for (int rb = 0; rb < 4; ++rb)
                acc[cl][rb] = __builtin_amdgcn_mfma_f32_16x16x32_bf16(afr[rb][s], bfr, acc[cl][rb], 0, 0, 0);
        }
    }

#pragma unroll
    for (int cl = 0; cl < 4; ++cl)
#pragma unroll
        for (int rb = 0; rb < 4; ++rb)
#pragma unroll
            for (int r = 0; r < 4; ++r) {
                int row = rb * 16 + (l >> 4) * 4 + r;
                if (row < nE)
                    Pb[(size_t)(e0 + row) * 256 + w * 64 + cl * 16 + (l & 15)] = (uint16_t)f2bf(acc[cl][rb][r]);
            }
}

// ---------------------------------------------------------------------------
// counting sort by e_ij: hist -> scan (3 kernels); scatter fused into kSA
// ---------------------------------------------------------------------------
__global__ void khist(const int* __restrict__ tbe, uint32_t* __restrict__ cnt, int T) {
    int t = blockIdx.x * blockDim.x + threadIdx.x;
    int stride = gridDim.x * blockDim.x;
    for (; t < T; t += stride) {
        int2 ee = ((const int2*)tbe)[t];
        atomicAdd(&cnt[ee.x], 1u);
    }
}

__global__ void scanA(const uint32_t* __restrict__ cnt, uint32_t* __restrict__ bsum, int E) {
    __shared__ uint32_t s[256];
    int tid = threadIdx.x;
    int e = blockIdx.x * 256 + tid;
    s[tid] = (e < E) ? cnt[e] : 0u;
    __syncthreads();
    for (int off = 128; off > 0; off >>= 1) {
        if (tid < off) s[tid] += s[tid + off];
        __syncthreads();
    }
    if (tid == 0) bsum[blockIdx.x] = s[0];
}

__global__ void scanB(uint32_t* __restrict__ bsum, int n) {
    __shared__ uint32_t s[512];
    int tid = threadIdx.x;
    s[tid] = (tid < n) ? bsum[tid] : 0u;
    __syncthreads();
    for (int off = 1; off < 512; off <<= 1) {
        uint32_t a = (tid >= off) ? s[tid - off] : 0u;
        __syncthreads();
        s[tid] += a;
        __syncthreads();
    }
    if (tid < n) bsum[tid] = (tid > 0) ? s[tid - 1] : 0u;
}

__global__ void scanC(const uint32_t* __restrict__ cnt, const uint32_t* __restrict__ bsum,
                      uint32_t* __restrict__ offs, int E) {
    __shared__ uint32_t s[256];
    int tid = threadIdx.x;
    int e = blockIdx.x * 256 + tid;
    uint32_t v = (e < E) ? cnt[e] : 0u;
    s[tid] = v;
    __syncthreads();
    for (int off = 1; off < 256; off <<= 1) {
        uint32_t a = (tid >= off) ? s[tid - off] : 0u;
        __syncthreads();
        s[tid] += a;
        __syncthreads();
    }
    if (e < E) offs[e] = bsum[blockIdx.x] + s[tid] - v;   // exclusive start
}

// ---------------------------------------------------------------------------
// kSA: fused scatter + angle MLP over the UNSORTED list; writes af (bf16
// pairs) and e2 at sorted pos. Afterwards offs[e] = segment END.
// ---------------------------------------------------------------------------
__global__ void __launch_bounds__(256) kSA(const int* __restrict__ tbe,
                                           const float* __restrict__ evec,
                                           const float* __restrict__ Wa1,
                                           const float* __restrict__ ba1,
                                           const float* __restrict__ Wa2,
                                           const float* __restrict__ ba2,
                                           uint32_t* __restrict__ offs,
                                           uint32_t* __restrict__ afpk,
                                           uint32_t* __restrict__ sortedE2, int T) {
    __shared__ float wa1_s[60], ba1_s[NB], wa2_s[400], ba2_s[NB];
    const int tid = threadIdx.x;
    for (int i = tid; i < 400; i += 256) wa2_s[i] = Wa2[i];
    if (tid < 60) wa1_s[tid] = Wa1[tid];
    if (tid < NB) { ba1_s[tid] = ba1[tid]; ba2_s[tid] = ba2[tid]; }
    __syncthreads();

    const int t = blockIdx.x * 256 + tid;
    if (t >= T) return;

    int2 ee = ((const int2*)tbe)[t];
    const float ax = evec[ee.x * 3], ay = evec[ee.x * 3 + 1], az = evec[ee.x * 3 + 2];
    const float bx = evec[ee.y * 3], by = evec[ee.y * 3 + 1], bz = evec[ee.y * 3 + 2];
    const float li = fmaxf(__builtin_amdgcn_sqrtf(ax * ax + ay * ay + az * az), 1e-6f);
    const float lk = fmaxf(__builtin_amdgcn_sqrtf(bx * bx + by * by + bz * bz), 1e-6f);
    float ct = (ax * bx + ay * by + az * bz) * __builtin_amdgcn_rcpf(li * lk);
    ct = fminf(fmaxf(ct, -1.f), 1.f);

    float h[NB];
#pragma unroll
    for (int o = 0; o < NB; ++o) {
        float z = fmaf(li, wa1_s[o], fmaf(lk, wa1_s[20 + o], fmaf(ct, wa1_s[40 + o], ba1_s[o])));
        h[o] = silu_f(z);
    }
    float af[NB];
#pragma unroll
    for (int o2 = 0; o2 < NB; ++o2) af[o2] = ba2_s[o2];
#pragma unroll
    for (int o = 0; o < NB; ++o) {
#pragma unroll
        for (int o2 = 0; o2 < NB; ++o2) af[o2] = fmaf(h[o], wa2_s[o * 20 + o2], af[o2]);
    }

    const uint32_t pos = atomicAdd(&offs[ee.x], 1u);
    sortedE2[pos] = (uint32_t)ee.y;
    uint32_t* dst = afpk + (size_t)pos * 10;
#pragma unroll
    for (int j = 0; j < 5; ++j) {
        uint2 pk;
        pk.x = pack_bf2(af[4 * j], af[4 * j + 1]);
        pk.y = pack_bf2(af[4 * j + 2], af[4 * j + 3]);
        *(uint2*)(dst + 2 * j) = pk;
    }
}

// ---------------------------------------------------------------------------
// kB5: one wave per edge. W1c regs from global; af staged UNPACKED fp32 in
// LDS (stride 20 floats = 80B, 16B aligned) -> 5x ds_read_b128 per triplet,
// conflict-free; 2-deep p2 prefetch; no atomics.
// ---------------------------------------------------------------------------
__global__ void __launch_bounds__(256) kB5(const uint32_t* __restrict__ sortedE2,
                                           const uint32_t* __restrict__ offs,
                                           const float* __restrict__ W1,
                                           const float* __restrict__ b1,
                                           const uint32_t* __restrict__ Ppk,
                                           const uint32_t* __restrict__ afpk,
                                           float* __restrict__ S, int E) {
    __shared__ __align__(16) float af_s[4][64 * 20];   // 20KB
    __shared__ uint32_t e2_s[4][64];

    const int tid = threadIdx.x;
    const int wave = tid >> 6, lane = tid & 63;
    const int e = blockIdx.x * 4 + wave;
    if (e >= E) return;   // no block barriers — safe divergence

    // W1c fragment (rows 256..275, cols 2*lane,2*lane+1) straight from global
    float2 wreg[NB];
#pragma unroll
    for (int k = 0; k < NB; ++k)
        wreg[k] = *(const float2*)(W1 + (size_t)(256 + k) * 128 + 2 * lane);

    const uint32_t start = (e > 0) ? offs[e - 1] : 0u;
    const uint32_t end = offs[e];
    const int n = (int)(end - start);

    const float2 b1v = ((const float2*)b1)[lane];
    const uint32_t p1 = Ppk[(size_t)e * 128 + lane];
    const float p1lo = bf_lo(p1) + b1v.x;
    const float p1hi = bf_hi(p1) + b1v.y;
    float acc0 = 0.f, acc1 = 0.f;

    float* afw = af_s[wave];

    for (int c0 = 0; c0 < n; c0 += 64) {
        const int m = min(64, n - c0);
        // stage af rows: read packed bf16 coalesced, write unpacked fp32
        const uint32_t base10 = (start + c0) * 10u;
        for (int i = lane; i < m * 10; i += 64) {
            const uint32_t u = afpk[base10 + i];
            afw[2 * i] = bf_lo(u);
            afw[2 * i + 1] = bf_hi(u);
        }
        if (lane < m) e2_s[wave][lane] = sortedE2[start + c0 + lane];
        // within-wave producer->consumer: drain ds_writes, pin ordering
        asm volatile("s_waitcnt lgkmcnt(0)" ::: "memory");
        __builtin_amdgcn_sched_barrier(0);

        uint32_t p2a = Ppk[(size_t)e2_s[wave][0] * 128 + 64 + lane];
        uint32_t p2b = (m > 1) ? Ppk[(size_t)e2_s[wave][1] * 128 + 64 + lane] : p2a;
        for (int i2 = 0; i2 < m; ++i2) {
            const uint32_t p2 = p2a;
            p2a = p2b;
            if (i2 + 2 < m) p2b = Ppk[(size_t)e2_s[wave][i2 + 2] * 128 + 64 + lane];
            float x0 = p1lo + bf_lo(p2);
            float x1 = p1hi + bf_hi(p2);
            const float4* afp = (const float4*)(afw + i2 * 20);
            const float4 fA = afp[0], fB = afp[1], fC = afp[2], fD = afp[3], fE = afp[4];
            const float a_[20] = {fA.x, fA.y, fA.z, fA.w, fB.x, fB.y, fB.z, fB.w,
                                  fC.x, fC.y, fC.z, fC.w, fD.x, fD.y, fD.z, fD.w,
                                  fE.x, fE.y, fE.z, fE.w};
#pragma unroll
            for (int j = 0; j < NB; ++j) {
                x0 = fmaf(a_[j], wreg[j].x, x0);
                x1 = fmaf(a_[j], wreg[j].y, x1);
            }
            acc0 += silu_f(x0);
            acc1 += silu_f(x1);
        }
    }
    float2 o;
    o.x = acc0;
    o.y = acc1;
    ((float2*)S)[(size_t)e * 64 + lane] = o;
}

// ---------------------------------------------------------------------------
// kC2: MFMA out = S @ M + cnt*cvec + bu, in-place. Block: 64 rows x 128 cols.
// ---------------------------------------------------------------------------
__global__ void __launch_bounds__(256) kC2(const float* __restrict__ S,
                                           const uint32_t* __restrict__ Mfrag,
                                           const float* __restrict__ cvec,
                                           const float* __restrict__ bu,
                                           const uint32_t* __restrict__ cnt,
                                           int E) {
    __shared__ uint32_t As[4096];    // 64 x 64 dwords swizzled (16KB)
    __shared__ uint32_t Bs[8192];    // 32KB fragment-ordered M
    __shared__ float cnt_s[64];
    const int tid = threadIdx.x;
    const int e0 = blockIdx.x * 64;
    const int nE = min(64, E - e0);

    for (int d = tid; d < 4096; d += 256) {
        int row = d >> 6, p = d & 63;
        int g = p >> 2;
        float2 v;
        if (row < nE) v = *(const float2*)(S + (size_t)(e0 + row) * 128 + 2 * p);
        else { v.x = 0.f; v.y = 0.f; }
        As[row * 64 + ((g ^ (row & 7)) << 2) + (p & 3)] = pack_bf2(v.x, v.y);
    }
    for (int d = tid; d < 2048; d += 256)
        ((uint4*)Bs)[d] = ((const uint4*)Mfrag)[d];
    if (tid < 64) cnt_s[tid] = (tid < nE) ? (float)cnt[e0 + tid] : 0.f;
    __syncthreads();

    const int w = tid >> 6, l = tid & 63;

    bf16x8 afr[4][4];
#pragma unroll
    for (int rb = 0; rb < 4; ++rb)
#pragma unroll
        for (int s = 0; s < 4; ++s) {
            int row = rb * 16 + (l & 15);
            int g = s * 4 + (l >> 4);
            afr[rb][s] = *(const bf16x8*)((const char*)As + row * 256 + ((g ^ (row & 7)) << 4));
        }

    f32x4 acc[2][4];
#pragma unroll
    for (int cl = 0; cl < 2; ++cl)
#pragma unroll
        for (int rb = 0; rb < 4; ++rb) acc[cl][rb] = (f32x4)(0.f);

#pragma unroll
    for (int cl = 0; cl < 2; ++cl) {
        const int c = w * 2 + cl;
#pragma unroll
        for (int s = 0; s < 4; ++s) {
            bf16x8 bfr = *(const bf16x8*)((const char*)Bs + (((s * 8 + c) * 64 + l) << 4));
#pragma unroll
            for (int rb = 0; rb < 4; ++rb)
                acc[cl][rb] = __builtin_amdgcn_mfma_f32_16x16x32_bf16(afr[rb][s], bfr, acc[cl][rb], 0, 0, 0);
        }
    }

    // epilogue: + cnt*cvec + bu, write fp32 in place
#pragma unroll
    for (int cl = 0; cl < 2; ++cl) {
        const int col = w * 32 + cl * 16 + (l & 15);
        const float cv = cvec[col];
        const float bv = bu[col];
#pragma unroll
        for (int rb = 0; rb < 4; ++rb)
#pragma unroll
            for (int r = 0; r < 4; ++r) {
                int row = rb * 16 + (l >> 4) * 4 + r;
                if (row < nE) {
                    float* dst = (float*)S + (size_t)(e0 + row) * 128 + col;
                    *dst = acc[cl][rb][r] + fmaf(cnt_s[row], cv, bv);
                }
            }
    }
}

// ---------------------------------------------------------------------------
extern "C" void kernel_launch(void* const* d_in, const int* in_sizes, int n_in,
                              void* d_out, int out_size, void* d_ws, size_t ws_size,
                              hipStream_t stream) {
    const float* edge_attr = (const float*)d_in[0];
    // d_in[1]: three_body_indices — unused by the reference computation
    const int* tbe = (const int*)d_in[2];
    const float* evec = (const float*)d_in[3];
    const float* Wa1 = (const float*)d_in[4];
    const float* ba1 = (const float*)d_in[5];
    const float* Wa2 = (const float*)d_in[6];
    const float* ba2 = (const float*)d_in[7];
    const float* W1 = (const float*)d_in[8];
    const float* b1 = (const float*)d_in[9];
    const float* W2 = (const float*)d_in[10];
    const float* b2 = (const float*)d_in[11];
    const float* Wu = (const float*)d_in[12];
    const float* bu = (const float*)d_in[13];

    const int E = in_sizes[0] / 128;
    const int T = in_sizes[2] / 2;
    float* S = (float*)d_out;

    const int nScanBlk = (E + 255) / 256;

    char* ws = (char*)d_ws;
    size_t off = 0;
    uint32_t* Ppk = (uint32_t*)(ws + off); off += (size_t)E * 512;    // bf16 E x 256
    uint32_t* cnt = (uint32_t*)(ws + off); off += (size_t)E * 4;
    uint32_t* offs = (uint32_t*)(ws + off); off += (size_t)E * 4;
    uint32_t* sortedE2 = (uint32_t*)(ws + off); off += (size_t)T * 4;
    uint32_t* afpk = (uint32_t*)(ws + off); off += (size_t)T * 40;
    uint32_t* bsum = (uint32_t*)(ws + off); off += (size_t)((nScanBlk + 3) & ~3) * 4;
    uint32_t* Bpk = (uint32_t*)(ws + off); off += 65536;
    float* Mf32 = (float*)(ws + off); off += 65536;
    uint32_t* Mfrag = (uint32_t*)(ws + off); off += 32768;
    float* cvec = (float*)(ws + off); off += 512;

    hipMemsetAsync(cnt, 0, (size_t)E * 4, stream);

    prep_kernel<<<129, 64, 0, stream>>>(W2, b2, Wu, Mf32, cvec);
    prep2<<<64, 256, 0, stream>>>(W1, Bpk);
    prepM<<<32, 256, 0, stream>>>(Mf32, Mfrag);
    kA3<<<(E + 63) / 64, 256, 0, stream>>>(edge_attr, Bpk, (uint16_t*)Ppk, E);
    khist<<<2048, 256, 0, stream>>>(tbe, cnt, T);
    scanA<<<nScanBlk, 256, 0, stream>>>(cnt, bsum, E);
    scanB<<<1, 512, 0, stream>>>(bsum, nScanBlk);
    scanC<<<nScanBlk, 256, 0, stream>>>(cnt, bsum, offs, E);
    kSA<<<(T + 255) / 256, 256, 0, stream>>>(tbe, evec, Wa1, ba1, Wa2, ba2,
                                             offs, afpk, sortedE2, T);
    kB5<<<(E + 3) / 4, 256, 0, stream>>>(sortedE2, offs, W1, b1, Ppk, afpk, S, E);
    kC2<<<(E + 63) / 64, 256, 0, stream>>>(S, Mfrag, cvec, bu, cnt, E);
}